// Round 3
// baseline (383.447 us; speedup 1.0000x reference)
//
#include <hip/hip_runtime.h>
#include <hip/hip_bf16.h>

// GCN 2-layer, N=20000, F_IN=512, H=256, C=40, E=640000, fp32 in/out.
// CSR build -> gemm1 (bf16 MFMA 64x256 tile, x@W1 -> h1b bf16)
//   -> agg1 (XCD-partitioned feature-quarter gather, +b1, relu -> hrb bf16)
//   -> gemm2 (bf16 MFMA 64x64, hrb@W2 -> h2b bf16, cols padded to 64)
//   -> agg2 (full-wave gather, +b2 -> out fp32)

#define N_NODES 20000
#define F_IN    512
#define H_DIM   256
#define C_DIM   40
#define C_PAD   64
#define E_EDGES 640000

typedef __attribute__((ext_vector_type(8))) short short8;
typedef __attribute__((ext_vector_type(4))) float floatx4;

__device__ __forceinline__ float bf2f(unsigned short u) {
    union { unsigned int i; float f; } v;
    v.i = ((unsigned int)u) << 16;
    return v.f;
}
__device__ __forceinline__ unsigned short f2bf(float f) {
    unsigned int u = __float_as_uint(f);
    unsigned int r = (u + 0x7fffu + ((u >> 16) & 1u)) >> 16;   // RNE
    return (unsigned short)r;
}

// ---------------- degree / CSR build ----------------

__global__ void count_kernel(const int* __restrict__ dst, int* __restrict__ cnt) {
    int e = blockIdx.x * blockDim.x + threadIdx.x;
    if (e < E_EDGES) atomicAdd(&cnt[dst[e]], 1);
}

// exclusive scan of cnt -> rowptr, plus dinv = rsqrt(cnt+1)
__global__ void scan_kernel(const int* __restrict__ cnt, int* __restrict__ rowptr,
                            float* __restrict__ dinv) {
    __shared__ int sums[256];
    const int t = threadIdx.x;
    const int CH = (N_NODES + 255) / 256;   // 79
    int begin = t * CH;
    int end = begin + CH; if (end > N_NODES) end = N_NODES;
    int s = 0;
    for (int i = begin; i < end; ++i) s += cnt[i];
    sums[t] = s;
    __syncthreads();
    if (t == 0) {
        int run = 0;
        for (int i = 0; i < 256; ++i) { int v = sums[i]; sums[i] = run; run += v; }
    }
    __syncthreads();
    int run = sums[t];
    for (int i = begin; i < end; ++i) {
        int c = cnt[i];
        rowptr[i] = run; run += c;
        dinv[i] = rsqrtf((float)c + 1.0f);
    }
    if (t == 0) rowptr[N_NODES] = E_EDGES;
}

__global__ void fill_kernel(const int* __restrict__ src, const int* __restrict__ dst,
                            const int* __restrict__ rowptr, int* __restrict__ cursor,
                            const float* __restrict__ dinv,
                            int* __restrict__ esrc, float* __restrict__ ecoef) {
    int e = blockIdx.x * blockDim.x + threadIdx.x;
    if (e < E_EDGES) {
        int s = src[e];
        int d = dst[e];
        int pos = atomicAdd(&cursor[d], 1);
        int idx = rowptr[d] + pos;
        esrc[idx] = s;
        ecoef[idx] = dinv[s] * dinv[d];
    }
}

// ---------------- weight prep: transpose + cast to bf16 ----------------

__global__ void w1t_kernel(const float* __restrict__ W1, unsigned short* __restrict__ w1t) {
    int idx = blockIdx.x * blockDim.x + threadIdx.x;   // 131072
    int n = idx >> 9, k = idx & 511;
    w1t[idx] = f2bf(W1[k * H_DIM + n]);
}

__global__ void w2t_kernel(const float* __restrict__ W2, unsigned short* __restrict__ w2t) {
    int idx = blockIdx.x * blockDim.x + threadIdx.x;   // 16384
    int n = idx >> 8, k = idx & 255;
    w2t[idx] = (n < C_DIM) ? f2bf(W2[k * C_DIM + n]) : (unsigned short)0;
}

// ---------------- gemm1: h1b[M,256] = bf16( x[M,512] @ W1 )  tile 64x256 ----------------
// Block = 256 thr = 4 waves. Wave w: rows [w*16,w*16+16) x all 256 cols (16 n-tiles).
// x read exactly once (grid = 313 row-blocks). LDS rows padded to 40 shorts (2-way max).

__global__ __launch_bounds__(256) void gemm1_kernel(const float* __restrict__ A,
                                                    const unsigned short* __restrict__ BT,
                                                    unsigned short* __restrict__ Cb) {
    __shared__ short As[64 * 40];    //  5.1 KB
    __shared__ short Bs[256 * 40];   // 20.5 KB
    const int tid = threadIdx.x;
    const int w = tid >> 6;
    const int lane = tid & 63;
    const int lq = lane >> 4;
    const int lm = lane & 15;
    const int row0 = blockIdx.x * 64;
    const int sr = tid >> 2;        // 0..63
    const int sc = (tid & 3) * 8;   // 0,8,16,24

    floatx4 acc[16];
#pragma unroll
    for (int t = 0; t < 16; ++t) acc[t] = (floatx4){0.f, 0.f, 0.f, 0.f};

    for (int k0 = 0; k0 < F_IN; k0 += 32) {
        // stage A (64 rows x 32 k), fp32 -> bf16
        {
            const int gr = row0 + sr;
            short8 av = (short8){0,0,0,0,0,0,0,0};
            if (gr < N_NODES) {
                const float* p = A + (size_t)gr * F_IN + k0 + sc;
                float4 a0 = *(const float4*)p;
                float4 a1 = *(const float4*)(p + 4);
                av[0] = (short)f2bf(a0.x); av[1] = (short)f2bf(a0.y);
                av[2] = (short)f2bf(a0.z); av[3] = (short)f2bf(a0.w);
                av[4] = (short)f2bf(a1.x); av[5] = (short)f2bf(a1.y);
                av[6] = (short)f2bf(a1.z); av[7] = (short)f2bf(a1.w);
            }
            *(short8*)&As[sr * 40 + sc] = av;
        }
        // stage B (256 n-rows x 32 k)
#pragma unroll
        for (int j = 0; j < 4; ++j) {
            int row = j * 64 + sr;
            *(short8*)&Bs[row * 40 + sc] = *(const short8*)&BT[(size_t)row * F_IN + k0 + sc];
        }
        __syncthreads();
        short8 af = *(const short8*)&As[(w * 16 + lm) * 40 + lq * 8];
#pragma unroll
        for (int t = 0; t < 16; ++t) {
            short8 bf = *(const short8*)&Bs[(t * 16 + lm) * 40 + lq * 8];
            acc[t] = __builtin_amdgcn_mfma_f32_16x16x32_bf16(af, bf, acc[t], 0, 0, 0);
        }
        __syncthreads();
    }
#pragma unroll
    for (int t = 0; t < 16; ++t) {
#pragma unroll
        for (int r = 0; r < 4; ++r) {
            int row = row0 + w * 16 + lq * 4 + r;
            int col = t * 16 + lm;
            if (row < N_NODES) Cb[(size_t)row * H_DIM + col] = f2bf(acc[t][r]);
        }
    }
}

// ---------------- gemm2: h2b[M,64] = bf16( hrb[M,256] @ W2 )  tile 64x64 ----------------

__global__ __launch_bounds__(256) void gemm2_kernel(const unsigned short* __restrict__ Ab,
                                                    const unsigned short* __restrict__ BT,
                                                    unsigned short* __restrict__ Cb) {
    __shared__ short As[64 * 40];
    __shared__ short Bs[64 * 40];
    const int tid = threadIdx.x;
    const int w = tid >> 6;
    const int lane = tid & 63;
    const int lq = lane >> 4;
    const int lm = lane & 15;
    const int row0 = blockIdx.x * 64;
    const int sr = tid >> 2;
    const int sc = (tid & 3) * 8;

    floatx4 acc[4];
#pragma unroll
    for (int t = 0; t < 4; ++t) acc[t] = (floatx4){0.f, 0.f, 0.f, 0.f};

    for (int k0 = 0; k0 < H_DIM; k0 += 32) {
        {
            const int gr = row0 + sr;
            short8 av = (short8){0,0,0,0,0,0,0,0};
            if (gr < N_NODES)
                av = *(const short8*)&Ab[(size_t)gr * H_DIM + k0 + sc];
            *(short8*)&As[sr * 40 + sc] = av;
            *(short8*)&Bs[sr * 40 + sc] = *(const short8*)&BT[(size_t)sr * H_DIM + k0 + sc];
        }
        __syncthreads();
        short8 af = *(const short8*)&As[(w * 16 + lm) * 40 + lq * 8];
#pragma unroll
        for (int t = 0; t < 4; ++t) {
            short8 bf = *(const short8*)&Bs[(t * 16 + lm) * 40 + lq * 8];
            acc[t] = __builtin_amdgcn_mfma_f32_16x16x32_bf16(af, bf, acc[t], 0, 0, 0);
        }
        __syncthreads();
    }
#pragma unroll
    for (int t = 0; t < 4; ++t) {
#pragma unroll
        for (int r = 0; r < 4; ++r) {
            int row = row0 + w * 16 + lq * 4 + r;
            int col = t * 16 + lm;
            if (row < N_NODES) Cb[(size_t)row * C_PAD + col] = f2bf(acc[t][r]);
        }
    }
}

// ---------------- agg1: XCD-partitioned feature-quarter gather ----------------
// Block b: quarter q = b&3 (so each XCD sees one 2.5MB slice of h1b under %8
// round-robin dispatch), nodes (b>>2)*4 + wave. Lane = 1 bf16 feature.
// Per edge: one 128B line from L2. esrc/ecoef via nontemporal loads.

__global__ __launch_bounds__(256) void agg1_kernel(const unsigned short* __restrict__ h1b,
                                                   const int* __restrict__ rowptr,
                                                   const int* __restrict__ esrc,
                                                   const float* __restrict__ ecoef,
                                                   const float* __restrict__ dinv,
                                                   const float* __restrict__ b1,
                                                   unsigned short* __restrict__ hrb) {
    const int b = blockIdx.x;
    const int q = b & 3;
    const int w = threadIdx.x >> 6;
    const int lane = threadIdx.x & 63;
    const int i = (b >> 2) * 4 + w;                 // node
    const int f = q * 64 + lane;                    // feature
    const float di = dinv[i];
    const int rb = rowptr[i], re = rowptr[i + 1];
    const unsigned short* __restrict__ hq = h1b + (size_t)q * 64;
    float acc = di * di * bf2f(h1b[(size_t)i * H_DIM + f]);
    int k = rb;
    for (; k + 3 < re; k += 4) {
        int s0 = __builtin_nontemporal_load(&esrc[k]);
        int s1 = __builtin_nontemporal_load(&esrc[k + 1]);
        int s2 = __builtin_nontemporal_load(&esrc[k + 2]);
        int s3 = __builtin_nontemporal_load(&esrc[k + 3]);
        float w0 = __builtin_nontemporal_load(&ecoef[k]);
        float w1 = __builtin_nontemporal_load(&ecoef[k + 1]);
        float w2 = __builtin_nontemporal_load(&ecoef[k + 2]);
        float w3 = __builtin_nontemporal_load(&ecoef[k + 3]);
        float v0 = bf2f(hq[((size_t)s0 << 8) + lane]);
        float v1 = bf2f(hq[((size_t)s1 << 8) + lane]);
        float v2 = bf2f(hq[((size_t)s2 << 8) + lane]);
        float v3 = bf2f(hq[((size_t)s3 << 8) + lane]);
        acc = fmaf(w0, v0, acc); acc = fmaf(w1, v1, acc);
        acc = fmaf(w2, v2, acc); acc = fmaf(w3, v3, acc);
    }
    for (; k < re; ++k) {
        int s = __builtin_nontemporal_load(&esrc[k]);
        float ww = __builtin_nontemporal_load(&ecoef[k]);
        acc = fmaf(ww, bf2f(hq[((size_t)s << 8) + lane]), acc);
    }
    acc = fmaxf(acc + b1[f], 0.f);
    hrb[(size_t)i * H_DIM + f] = f2bf(acc);
}

// ---------------- agg2: wave/node, 64-lane gather of h2b, +b2 -> out fp32 ----------------

__global__ __launch_bounds__(256) void agg2_kernel(const unsigned short* __restrict__ h2b,
                                                   const int* __restrict__ rowptr,
                                                   const int* __restrict__ esrc,
                                                   const float* __restrict__ ecoef,
                                                   const float* __restrict__ dinv,
                                                   const float* __restrict__ b2,
                                                   float* __restrict__ out) {
    const int i = (blockIdx.x * 256 + threadIdx.x) >> 6;   // node
    const int lane = threadIdx.x & 63;
    const float di = dinv[i];
    const int rb = rowptr[i], re = rowptr[i + 1];
    float acc = di * di * bf2f(h2b[((size_t)i << 6) + lane]);
    int k = rb;
    for (; k + 3 < re; k += 4) {
        int s0 = __builtin_nontemporal_load(&esrc[k]);
        int s1 = __builtin_nontemporal_load(&esrc[k + 1]);
        int s2 = __builtin_nontemporal_load(&esrc[k + 2]);
        int s3 = __builtin_nontemporal_load(&esrc[k + 3]);
        float w0 = __builtin_nontemporal_load(&ecoef[k]);
        float w1 = __builtin_nontemporal_load(&ecoef[k + 1]);
        float w2 = __builtin_nontemporal_load(&ecoef[k + 2]);
        float w3 = __builtin_nontemporal_load(&ecoef[k + 3]);
        float v0 = bf2f(h2b[((size_t)s0 << 6) + lane]);
        float v1 = bf2f(h2b[((size_t)s1 << 6) + lane]);
        float v2 = bf2f(h2b[((size_t)s2 << 6) + lane]);
        float v3 = bf2f(h2b[((size_t)s3 << 6) + lane]);
        acc = fmaf(w0, v0, acc); acc = fmaf(w1, v1, acc);
        acc = fmaf(w2, v2, acc); acc = fmaf(w3, v3, acc);
    }
    for (; k < re; ++k) {
        int s = __builtin_nontemporal_load(&esrc[k]);
        float ww = __builtin_nontemporal_load(&ecoef[k]);
        acc = fmaf(ww, bf2f(h2b[((size_t)s << 6) + lane]), acc);
    }
    if (lane < C_DIM) out[(size_t)i * C_DIM + lane] = acc + b2[lane];
}

// ---------------- launch ----------------

extern "C" void kernel_launch(void* const* d_in, const int* in_sizes, int n_in,
                              void* d_out, int out_size, void* d_ws, size_t ws_size,
                              hipStream_t stream) {
    const float* x   = (const float*)d_in[0];
    const int*   ei  = (const int*)d_in[1];
    const float* W1  = (const float*)d_in[2];
    const float* b1  = (const float*)d_in[3];
    const float* W2  = (const float*)d_in[4];
    const float* b2  = (const float*)d_in[5];
    float* out = (float*)d_out;

    const int* src = ei;            // edge_index[0]
    const int* dst = ei + E_EDGES;  // edge_index[1]

    // workspace layout, all offsets 128B-aligned. Total ~28.8 MB.
    char* ws = (char*)d_ws;
    int*            cnt    = (int*)(ws + 0);
    float*          dinv   = (float*)(ws + 80128);
    int*            rowptr = (int*)(ws + 160256);
    int*            cursor = (int*)(ws + 240384);
    int*            esrc   = (int*)(ws + 320512);
    float*          ecoef  = (float*)(ws + 2880512);
    unsigned short* w1t    = (unsigned short*)(ws + 5440512);
    unsigned short* w2t    = (unsigned short*)(ws + 5702656);
    unsigned short* h1b    = (unsigned short*)(ws + 5735424);
    unsigned short* hrb    = (unsigned short*)(ws + 15975424);
    unsigned short* h2b    = (unsigned short*)(ws + 26215424);

    hipMemsetAsync(cnt, 0, N_NODES * sizeof(int), stream);
    hipMemsetAsync(cursor, 0, N_NODES * sizeof(int), stream);

    count_kernel<<<(E_EDGES + 255) / 256, 256, 0, stream>>>(dst, cnt);
    scan_kernel<<<1, 256, 0, stream>>>(cnt, rowptr, dinv);
    fill_kernel<<<(E_EDGES + 255) / 256, 256, 0, stream>>>(src, dst, rowptr, cursor, dinv,
                                                           esrc, ecoef);

    w1t_kernel<<<(F_IN * H_DIM) / 256, 256, 0, stream>>>(W1, w1t);
    w2t_kernel<<<(H_DIM * C_PAD) / 256, 256, 0, stream>>>(W2, w2t);

    gemm1_kernel<<<(N_NODES + 63) / 64, 256, 0, stream>>>(x, w1t, h1b);

    agg1_kernel<<<N_NODES, 256, 0, stream>>>(h1b, rowptr, esrc, ecoef, dinv, b1, hrb);

    gemm2_kernel<<<(N_NODES + 63) / 64, 256, 0, stream>>>(hrb, w2t, h2b);

    agg2_kernel<<<N_NODES / 4, 256, 0, stream>>>(h2b, rowptr, esrc, ecoef, dinv, b2, out);
}

// Round 4
// 336.438 us; speedup vs baseline: 1.1397x; 1.1397x over previous
//
#include <hip/hip_runtime.h>
#include <hip/hip_bf16.h>

// GCN 2-layer, N=20000, F_IN=512, H=256, C=40, E=640000, fp32 in/out.
// CSR build (edata = {src, coef} int2) -> gemm1 (bf16 MFMA 64x256, x@W1 -> h1b)
//   -> agg1 (XCD quarter-sliced, 4 edges/wave-instr, +b1, relu -> hrb)
//   -> gemm2 (bf16 MFMA 64x64 -> h2b, cols padded to 64)
//   -> agg2 (2 edges/wave-instr, +b2 -> out fp32)

#define N_NODES 20000
#define F_IN    512
#define H_DIM   256
#define C_DIM   40
#define C_PAD   64
#define E_EDGES 640000

typedef __attribute__((ext_vector_type(8))) short short8;
typedef __attribute__((ext_vector_type(4))) float floatx4;

__device__ __forceinline__ float bf2f(unsigned short u) {
    union { unsigned int i; float f; } v;
    v.i = ((unsigned int)u) << 16;
    return v.f;
}
__device__ __forceinline__ unsigned short f2bf(float f) {
    unsigned int u = __float_as_uint(f);
    unsigned int r = (u + 0x7fffu + ((u >> 16) & 1u)) >> 16;   // RNE
    return (unsigned short)r;
}

// ---------------- degree / CSR build ----------------

__global__ void count_kernel(const int* __restrict__ dst, int* __restrict__ cnt) {
    int e = blockIdx.x * blockDim.x + threadIdx.x;
    if (e < E_EDGES) atomicAdd(&cnt[dst[e]], 1);
}

// exclusive scan of cnt -> rowptr, plus dinv = rsqrt(cnt+1)
__global__ void scan_kernel(const int* __restrict__ cnt, int* __restrict__ rowptr,
                            float* __restrict__ dinv) {
    __shared__ int sums[256];
    const int t = threadIdx.x;
    const int CH = (N_NODES + 255) / 256;   // 79
    int begin = t * CH;
    int end = begin + CH; if (end > N_NODES) end = N_NODES;
    int s = 0;
    for (int i = begin; i < end; ++i) s += cnt[i];
    sums[t] = s;
    __syncthreads();
    if (t == 0) {
        int run = 0;
        for (int i = 0; i < 256; ++i) { int v = sums[i]; sums[i] = run; run += v; }
    }
    __syncthreads();
    int run = sums[t];
    for (int i = begin; i < end; ++i) {
        int c = cnt[i];
        rowptr[i] = run; run += c;
        dinv[i] = rsqrtf((float)c + 1.0f);
    }
    if (t == 0) rowptr[N_NODES] = E_EDGES;
}

__global__ void fill_kernel(const int* __restrict__ src, const int* __restrict__ dst,
                            const int* __restrict__ rowptr, int* __restrict__ cursor,
                            const float* __restrict__ dinv,
                            int2* __restrict__ edata) {
    int e = blockIdx.x * blockDim.x + threadIdx.x;
    if (e < E_EDGES) {
        int s = src[e];
        int d = dst[e];
        int pos = atomicAdd(&cursor[d], 1);
        float w = dinv[s] * dinv[d];
        edata[rowptr[d] + pos] = make_int2(s, __float_as_int(w));
    }
}

// zero the 16-entry slack past edata[E] so unconditional group loads are safe
__global__ void edata_pad_kernel(int2* __restrict__ edata) {
    int t = threadIdx.x;
    if (t < 16) edata[E_EDGES + t] = make_int2(0, 0);
}

// ---------------- weight prep: transpose + cast to bf16 ----------------

__global__ void w1t_kernel(const float* __restrict__ W1, unsigned short* __restrict__ w1t) {
    int idx = blockIdx.x * blockDim.x + threadIdx.x;   // 131072
    int n = idx >> 9, k = idx & 511;
    w1t[idx] = f2bf(W1[k * H_DIM + n]);
}

__global__ void w2t_kernel(const float* __restrict__ W2, unsigned short* __restrict__ w2t) {
    int idx = blockIdx.x * blockDim.x + threadIdx.x;   // 16384
    int n = idx >> 8, k = idx & 255;
    w2t[idx] = (n < C_DIM) ? f2bf(W2[k * C_DIM + n]) : (unsigned short)0;
}

// ---------------- gemm1: h1b[M,256] = bf16( x[M,512] @ W1 )  tile 64x256 ----------------

__global__ __launch_bounds__(256) void gemm1_kernel(const float* __restrict__ A,
                                                    const unsigned short* __restrict__ BT,
                                                    unsigned short* __restrict__ Cb) {
    __shared__ short As[64 * 40];
    __shared__ short Bs[256 * 40];
    const int tid = threadIdx.x;
    const int w = tid >> 6;
    const int lane = tid & 63;
    const int lq = lane >> 4;
    const int lm = lane & 15;
    const int row0 = blockIdx.x * 64;
    const int sr = tid >> 2;        // 0..63
    const int sc = (tid & 3) * 8;   // 0,8,16,24

    floatx4 acc[16];
#pragma unroll
    for (int t = 0; t < 16; ++t) acc[t] = (floatx4){0.f, 0.f, 0.f, 0.f};

    for (int k0 = 0; k0 < F_IN; k0 += 32) {
        {
            const int gr = row0 + sr;
            short8 av = (short8){0,0,0,0,0,0,0,0};
            if (gr < N_NODES) {
                const float* p = A + (size_t)gr * F_IN + k0 + sc;
                float4 a0 = *(const float4*)p;
                float4 a1 = *(const float4*)(p + 4);
                av[0] = (short)f2bf(a0.x); av[1] = (short)f2bf(a0.y);
                av[2] = (short)f2bf(a0.z); av[3] = (short)f2bf(a0.w);
                av[4] = (short)f2bf(a1.x); av[5] = (short)f2bf(a1.y);
                av[6] = (short)f2bf(a1.z); av[7] = (short)f2bf(a1.w);
            }
            *(short8*)&As[sr * 40 + sc] = av;
        }
#pragma unroll
        for (int j = 0; j < 4; ++j) {
            int row = j * 64 + sr;
            *(short8*)&Bs[row * 40 + sc] = *(const short8*)&BT[(size_t)row * F_IN + k0 + sc];
        }
        __syncthreads();
        short8 af = *(const short8*)&As[(w * 16 + lm) * 40 + lq * 8];
#pragma unroll
        for (int t = 0; t < 16; ++t) {
            short8 bf = *(const short8*)&Bs[(t * 16 + lm) * 40 + lq * 8];
            acc[t] = __builtin_amdgcn_mfma_f32_16x16x32_bf16(af, bf, acc[t], 0, 0, 0);
        }
        __syncthreads();
    }
#pragma unroll
    for (int t = 0; t < 16; ++t) {
#pragma unroll
        for (int r = 0; r < 4; ++r) {
            int row = row0 + w * 16 + lq * 4 + r;
            int col = t * 16 + lm;
            if (row < N_NODES) Cb[(size_t)row * H_DIM + col] = f2bf(acc[t][r]);
        }
    }
}

// ---------------- gemm2: h2b[M,64] = bf16( hrb[M,256] @ W2 )  tile 64x64 ----------------

__global__ __launch_bounds__(256) void gemm2_kernel(const unsigned short* __restrict__ Ab,
                                                    const unsigned short* __restrict__ BT,
                                                    unsigned short* __restrict__ Cb) {
    __shared__ short As[64 * 40];
    __shared__ short Bs[64 * 40];
    const int tid = threadIdx.x;
    const int w = tid >> 6;
    const int lane = tid & 63;
    const int lq = lane >> 4;
    const int lm = lane & 15;
    const int row0 = blockIdx.x * 64;
    const int sr = tid >> 2;
    const int sc = (tid & 3) * 8;

    floatx4 acc[4];
#pragma unroll
    for (int t = 0; t < 4; ++t) acc[t] = (floatx4){0.f, 0.f, 0.f, 0.f};

    for (int k0 = 0; k0 < H_DIM; k0 += 32) {
        {
            const int gr = row0 + sr;
            short8 av = (short8){0,0,0,0,0,0,0,0};
            if (gr < N_NODES)
                av = *(const short8*)&Ab[(size_t)gr * H_DIM + k0 + sc];
            *(short8*)&As[sr * 40 + sc] = av;
            *(short8*)&Bs[sr * 40 + sc] = *(const short8*)&BT[(size_t)sr * H_DIM + k0 + sc];
        }
        __syncthreads();
        short8 af = *(const short8*)&As[(w * 16 + lm) * 40 + lq * 8];
#pragma unroll
        for (int t = 0; t < 4; ++t) {
            short8 bf = *(const short8*)&Bs[(t * 16 + lm) * 40 + lq * 8];
            acc[t] = __builtin_amdgcn_mfma_f32_16x16x32_bf16(af, bf, acc[t], 0, 0, 0);
        }
        __syncthreads();
    }
#pragma unroll
    for (int t = 0; t < 4; ++t) {
#pragma unroll
        for (int r = 0; r < 4; ++r) {
            int row = row0 + w * 16 + lq * 4 + r;
            int col = t * 16 + lm;
            if (row < N_NODES) Cb[(size_t)row * C_PAD + col] = f2bf(acc[t][r]);
        }
    }
}

// ---------------- agg1: quarter-sliced, 4 edges per wave-instruction ----------------
// Block b: quarter q=b&3 (XCD %8 round-robin -> 2 XCDs per 2.5MB h1b slice),
// node i=(b>>2)*4+wave. Wave: 4 groups of 16 lanes, group g handles edge k+g,
// lane covers 4 features (short4, 8B). Cross-group reduce via shfl_xor(16,32).

__global__ __launch_bounds__(256) void agg1_kernel(const unsigned short* __restrict__ h1b,
                                                   const int* __restrict__ rowptr,
                                                   const int2* __restrict__ edata,
                                                   const float* __restrict__ dinv,
                                                   const float* __restrict__ b1,
                                                   unsigned short* __restrict__ hrb) {
    const int b = blockIdx.x;
    const int q = b & 3;
    const int w = threadIdx.x >> 6;
    const int lane = threadIdx.x & 63;
    const int g = lane >> 4;          // edge group 0..3
    const int lm = lane & 15;
    const int i = (b >> 2) * 4 + w;   // node
    const int fbase = q * 64 + lm * 4;
    const int rb = rowptr[i], re = rowptr[i + 1];
    float ax = 0.f, ay = 0.f, az = 0.f, aw = 0.f;
    for (int k = rb; k < re; k += 4) {
        const int idx = k + g;
        int2 e = edata[idx];                         // slack-padded, safe
        const bool valid = idx < re;
        const int s = valid ? e.x : 0;
        const float wgt = valid ? __int_as_float(e.y) : 0.f;
        ushort4 v = *(const ushort4*)&h1b[((size_t)s << 8) + fbase];
        ax = fmaf(wgt, bf2f(v.x), ax);
        ay = fmaf(wgt, bf2f(v.y), ay);
        az = fmaf(wgt, bf2f(v.z), az);
        aw = fmaf(wgt, bf2f(v.w), aw);
    }
    // reduce across groups (lane bits 4 and 5)
    ax += __shfl_xor(ax, 16, 64); ay += __shfl_xor(ay, 16, 64);
    az += __shfl_xor(az, 16, 64); aw += __shfl_xor(aw, 16, 64);
    ax += __shfl_xor(ax, 32, 64); ay += __shfl_xor(ay, 32, 64);
    az += __shfl_xor(az, 32, 64); aw += __shfl_xor(aw, 32, 64);
    if (lane < 16) {
        const float di = dinv[i];
        const float ws = di * di;
        ushort4 sv = *(const ushort4*)&h1b[((size_t)i << 8) + fbase];
        ax = fmaf(ws, bf2f(sv.x), ax);
        ay = fmaf(ws, bf2f(sv.y), ay);
        az = fmaf(ws, bf2f(sv.z), az);
        aw = fmaf(ws, bf2f(sv.w), aw);
        float4 bb = *(const float4*)&b1[fbase];
        ax = fmaxf(ax + bb.x, 0.f); ay = fmaxf(ay + bb.y, 0.f);
        az = fmaxf(az + bb.z, 0.f); aw = fmaxf(aw + bb.w, 0.f);
        ushort4 o = make_ushort4(f2bf(ax), f2bf(ay), f2bf(az), f2bf(aw));
        *(ushort4*)&hrb[((size_t)i << 8) + fbase] = o;
    }
}

// ---------------- agg2: wave/node, 2 edges per wave-instruction ----------------

__global__ __launch_bounds__(256) void agg2_kernel(const unsigned short* __restrict__ h2b,
                                                   const int* __restrict__ rowptr,
                                                   const int2* __restrict__ edata,
                                                   const float* __restrict__ dinv,
                                                   const float* __restrict__ b2,
                                                   float* __restrict__ out) {
    const int i = (blockIdx.x * 256 + threadIdx.x) >> 6;   // node
    const int lane = threadIdx.x & 63;
    const int g = lane >> 5;          // edge group 0..1
    const int lm = lane & 31;
    const int c0 = lm * 2;            // feature pair in padded 64-col row
    const int rb = rowptr[i], re = rowptr[i + 1];
    float a0 = 0.f, a1 = 0.f;
    for (int k = rb; k < re; k += 2) {
        const int idx = k + g;
        int2 e = edata[idx];
        const bool valid = idx < re;
        const int s = valid ? e.x : 0;
        const float wgt = valid ? __int_as_float(e.y) : 0.f;
        unsigned int v = *(const unsigned int*)&h2b[((size_t)s << 6) + c0];
        a0 = fmaf(wgt, bf2f((unsigned short)(v & 0xffff)), a0);
        a1 = fmaf(wgt, bf2f((unsigned short)(v >> 16)), a1);
    }
    a0 += __shfl_xor(a0, 32, 64);
    a1 += __shfl_xor(a1, 32, 64);
    if (lane < 20) {
        const float di = dinv[i];
        const float ws = di * di;
        unsigned int sv = *(const unsigned int*)&h2b[((size_t)i << 6) + c0];
        a0 = fmaf(ws, bf2f((unsigned short)(sv & 0xffff)), a0);
        a1 = fmaf(ws, bf2f((unsigned short)(sv >> 16)), a1);
        float2 bb = *(const float2*)&b2[c0];
        *(float2*)&out[(size_t)i * C_DIM + c0] = make_float2(a0 + bb.x, a1 + bb.y);
    }
}

// ---------------- launch ----------------

extern "C" void kernel_launch(void* const* d_in, const int* in_sizes, int n_in,
                              void* d_out, int out_size, void* d_ws, size_t ws_size,
                              hipStream_t stream) {
    const float* x   = (const float*)d_in[0];
    const int*   ei  = (const int*)d_in[1];
    const float* W1  = (const float*)d_in[2];
    const float* b1  = (const float*)d_in[3];
    const float* W2  = (const float*)d_in[4];
    const float* b2  = (const float*)d_in[5];
    float* out = (float*)d_out;

    const int* src = ei;            // edge_index[0]
    const int* dst = ei + E_EDGES;  // edge_index[1]

    // workspace layout, 128B-aligned offsets. Total ~28.8 MB.
    char* ws = (char*)d_ws;
    int*            cnt    = (int*)(ws + 0);          //   80000 B
    float*          dinv   = (float*)(ws + 80128);    //   80000 B
    int*            rowptr = (int*)(ws + 160256);     //   80004 B
    int*            cursor = (int*)(ws + 240384);     //   80000 B
    int2*           edata  = (int2*)(ws + 320512);    // (E+16)*8 = 5120128 B
    unsigned short* w1t    = (unsigned short*)(ws + 5440640);   //   262144 B
    unsigned short* w2t    = (unsigned short*)(ws + 5702784);   //    32768 B
    unsigned short* h1b    = (unsigned short*)(ws + 5735552);   // 10240000 B
    unsigned short* hrb    = (unsigned short*)(ws + 15975552);  // 10240000 B
    unsigned short* h2b    = (unsigned short*)(ws + 26215552);  //  2560000 B

    hipMemsetAsync(cnt, 0, N_NODES * sizeof(int), stream);
    hipMemsetAsync(cursor, 0, N_NODES * sizeof(int), stream);

    count_kernel<<<(E_EDGES + 255) / 256, 256, 0, stream>>>(dst, cnt);
    scan_kernel<<<1, 256, 0, stream>>>(cnt, rowptr, dinv);
    fill_kernel<<<(E_EDGES + 255) / 256, 256, 0, stream>>>(src, dst, rowptr, cursor, dinv,
                                                           edata);
    edata_pad_kernel<<<1, 64, 0, stream>>>(edata);

    w1t_kernel<<<(F_IN * H_DIM) / 256, 256, 0, stream>>>(W1, w1t);
    w2t_kernel<<<(H_DIM * C_PAD) / 256, 256, 0, stream>>>(W2, w2t);

    gemm1_kernel<<<(N_NODES + 63) / 64, 256, 0, stream>>>(x, w1t, h1b);

    agg1_kernel<<<N_NODES, 256, 0, stream>>>(h1b, rowptr, edata, dinv, b1, hrb);

    gemm2_kernel<<<(N_NODES + 63) / 64, 256, 0, stream>>>(hrb, w2t, h2b);

    agg2_kernel<<<N_NODES / 4, 256, 0, stream>>>(h2b, rowptr, edata, dinv, b2, out);
}

// Round 5
// 247.495 us; speedup vs baseline: 1.5493x; 1.3594x over previous
//
#include <hip/hip_runtime.h>
#include <hip/hip_bf16.h>

// GCN 2-layer, N=20000, F_IN=512, H=256, C=40, E=640000, fp32 in/out.
// count -> bsum/rowptr (parallel scan, cursor=rowptr) -> fill (edata={src,coef})
//   -> gemm1 (bf16 MFMA 64x256, x@W1 -> h1b) -> agg1 (quarter-sliced, 8 edges/instr)
//   -> gemm2 (bf16 MFMA 64x64 -> h2b 64-pad) -> agg2 (8 edges/instr) -> out fp32

#define N_NODES 20000
#define F_IN    512
#define H_DIM   256
#define C_DIM   40
#define C_PAD   64
#define E_EDGES 640000
#define NBLK    80
#define CHUNK   250

typedef __attribute__((ext_vector_type(8))) short short8;
typedef __attribute__((ext_vector_type(8))) unsigned short ushort8_t;
typedef __attribute__((ext_vector_type(4))) float floatx4;

__device__ __forceinline__ float bf2f(unsigned short u) {
    union { unsigned int i; float f; } v;
    v.i = ((unsigned int)u) << 16;
    return v.f;
}
__device__ __forceinline__ unsigned short f2bf(float f) {
    unsigned int u = __float_as_uint(f);
    unsigned int r = (u + 0x7fffu + ((u >> 16) & 1u)) >> 16;   // RNE
    return (unsigned short)r;
}

// ---------------- degree / CSR build ----------------

__global__ void count_kernel(const int* __restrict__ dst, int* __restrict__ cnt) {
    int e = blockIdx.x * blockDim.x + threadIdx.x;
    if (e < E_EDGES) atomicAdd(&cnt[dst[e]], 1);
}

// per-block sums of cnt (80 blocks x 250)
__global__ __launch_bounds__(256) void bsum_kernel(const int* __restrict__ cnt,
                                                   int* __restrict__ bsum) {
    __shared__ int red[256];
    const int t = threadIdx.x, j = blockIdx.x;
    red[t] = (t < CHUNK) ? cnt[j * CHUNK + t] : 0;
    __syncthreads();
    for (int s = 128; s > 0; s >>= 1) {
        if (t < s) red[t] += red[t + s];
        __syncthreads();
    }
    if (t == 0) bsum[j] = red[0];
}

// rowptr/cursor/dinv: each block reduces bsum[<j] for its offset, then LDS-scans its chunk
__global__ __launch_bounds__(256) void rowptr_kernel(const int* __restrict__ cnt,
                                                     const int* __restrict__ bsum,
                                                     int* __restrict__ rowptr,
                                                     int* __restrict__ cursor,
                                                     float* __restrict__ dinv) {
    __shared__ int red[128];
    __shared__ int sc[256];
    const int t = threadIdx.x, j = blockIdx.x;
    if (t < 128) red[t] = (t < NBLK && t < j) ? bsum[t] : 0;
    __syncthreads();
    for (int s = 64; s > 0; s >>= 1) {
        if (t < s) red[t] += red[t + s];
        __syncthreads();
    }
    const int boff = red[0];
    const int c = (t < CHUNK) ? cnt[j * CHUNK + t] : 0;
    sc[t] = c;
    __syncthreads();
    for (int s = 1; s < 256; s <<= 1) {      // Hillis-Steele inclusive scan
        int add = (t >= s) ? sc[t - s] : 0;
        __syncthreads();
        sc[t] += add;
        __syncthreads();
    }
    if (t < CHUNK) {
        int idx = j * CHUNK + t;
        int rp = boff + sc[t] - c;           // exclusive
        rowptr[idx] = rp;
        cursor[idx] = rp;
        dinv[idx] = rsqrtf((float)c + 1.0f);
    }
    if (j == NBLK - 1 && t == 0) rowptr[N_NODES] = E_EDGES;
}

// cursor pre-seeded with rowptr -> atomicAdd returns absolute slot
__global__ void fill_kernel(const int* __restrict__ src, const int* __restrict__ dst,
                            int* __restrict__ cursor, const float* __restrict__ dinv,
                            int2* __restrict__ edata) {
    int e = blockIdx.x * blockDim.x + threadIdx.x;
    if (e < E_EDGES) {
        int s = src[e];
        int d = dst[e];
        int idx = atomicAdd(&cursor[d], 1);
        edata[idx] = make_int2(s, __float_as_int(dinv[s] * dinv[d]));
    } else if (e < E_EDGES + 16) {
        edata[e] = make_int2(0, 0);          // slack for unconditional prefetch
    }
}

// ---------------- weight prep (merged): w1t[n][k], w2t 64-pad ----------------

__global__ void wt_kernel(const float* __restrict__ W1, const float* __restrict__ W2,
                          unsigned short* __restrict__ w1t, unsigned short* __restrict__ w2t) {
    int idx = blockIdx.x * blockDim.x + threadIdx.x;   // 147456 total
    if (idx < F_IN * H_DIM) {
        int n = idx >> 9, k = idx & 511;
        w1t[idx] = f2bf(W1[k * H_DIM + n]);
    } else {
        int id2 = idx - F_IN * H_DIM;
        int n = id2 >> 8, k = id2 & 255;
        w2t[id2] = (n < C_DIM) ? f2bf(W2[k * C_DIM + n]) : (unsigned short)0;
    }
}

// ---------------- gemm1: h1b[M,256] = bf16( x[M,512] @ W1 )  tile 64x256 ----------------

__global__ __launch_bounds__(256) void gemm1_kernel(const float* __restrict__ A,
                                                    const unsigned short* __restrict__ BT,
                                                    unsigned short* __restrict__ Cb) {
    __shared__ short As[64 * 40];
    __shared__ short Bs[256 * 40];
    const int tid = threadIdx.x;
    const int w = tid >> 6;
    const int lane = tid & 63;
    const int lq = lane >> 4;
    const int lm = lane & 15;
    const int row0 = blockIdx.x * 64;
    const int sr = tid >> 2;        // 0..63
    const int sc = (tid & 3) * 8;   // 0,8,16,24

    floatx4 acc[16];
#pragma unroll
    for (int t = 0; t < 16; ++t) acc[t] = (floatx4){0.f, 0.f, 0.f, 0.f};

    for (int k0 = 0; k0 < F_IN; k0 += 32) {
        {
            const int gr = row0 + sr;
            short8 av = (short8){0,0,0,0,0,0,0,0};
            if (gr < N_NODES) {
                const float* p = A + (size_t)gr * F_IN + k0 + sc;
                float4 a0 = *(const float4*)p;
                float4 a1 = *(const float4*)(p + 4);
                av[0] = (short)f2bf(a0.x); av[1] = (short)f2bf(a0.y);
                av[2] = (short)f2bf(a0.z); av[3] = (short)f2bf(a0.w);
                av[4] = (short)f2bf(a1.x); av[5] = (short)f2bf(a1.y);
                av[6] = (short)f2bf(a1.z); av[7] = (short)f2bf(a1.w);
            }
            *(short8*)&As[sr * 40 + sc] = av;
        }
#pragma unroll
        for (int j = 0; j < 4; ++j) {
            int row = j * 64 + sr;
            *(short8*)&Bs[row * 40 + sc] = *(const short8*)&BT[(size_t)row * F_IN + k0 + sc];
        }
        __syncthreads();
        short8 af = *(const short8*)&As[(w * 16 + lm) * 40 + lq * 8];
#pragma unroll
        for (int t = 0; t < 16; ++t) {
            short8 bf = *(const short8*)&Bs[(t * 16 + lm) * 40 + lq * 8];
            acc[t] = __builtin_amdgcn_mfma_f32_16x16x32_bf16(af, bf, acc[t], 0, 0, 0);
        }
        __syncthreads();
    }
#pragma unroll
    for (int t = 0; t < 16; ++t) {
#pragma unroll
        for (int r = 0; r < 4; ++r) {
            int row = row0 + w * 16 + lq * 4 + r;
            int col = t * 16 + lm;
            if (row < N_NODES) Cb[(size_t)row * H_DIM + col] = f2bf(acc[t][r]);
        }
    }
}

// ---------------- gemm2: h2b[M,64] = bf16( hrb[M,256] @ W2 )  tile 64x64 ----------------

__global__ __launch_bounds__(256) void gemm2_kernel(const unsigned short* __restrict__ Ab,
                                                    const unsigned short* __restrict__ BT,
                                                    unsigned short* __restrict__ Cb) {
    __shared__ short As[64 * 40];
    __shared__ short Bs[64 * 40];
    const int tid = threadIdx.x;
    const int w = tid >> 6;
    const int lane = tid & 63;
    const int lq = lane >> 4;
    const int lm = lane & 15;
    const int row0 = blockIdx.x * 64;
    const int sr = tid >> 2;
    const int sc = (tid & 3) * 8;

    floatx4 acc[4];
#pragma unroll
    for (int t = 0; t < 4; ++t) acc[t] = (floatx4){0.f, 0.f, 0.f, 0.f};

    for (int k0 = 0; k0 < H_DIM; k0 += 32) {
        {
            const int gr = row0 + sr;
            short8 av = (short8){0,0,0,0,0,0,0,0};
            if (gr < N_NODES)
                av = *(const short8*)&Ab[(size_t)gr * H_DIM + k0 + sc];
            *(short8*)&As[sr * 40 + sc] = av;
            *(short8*)&Bs[sr * 40 + sc] = *(const short8*)&BT[(size_t)sr * H_DIM + k0 + sc];
        }
        __syncthreads();
        short8 af = *(const short8*)&As[(w * 16 + lm) * 40 + lq * 8];
#pragma unroll
        for (int t = 0; t < 4; ++t) {
            short8 bf = *(const short8*)&Bs[(t * 16 + lm) * 40 + lq * 8];
            acc[t] = __builtin_amdgcn_mfma_f32_16x16x32_bf16(af, bf, acc[t], 0, 0, 0);
        }
        __syncthreads();
    }
#pragma unroll
    for (int t = 0; t < 4; ++t) {
#pragma unroll
        for (int r = 0; r < 4; ++r) {
            int row = row0 + w * 16 + lq * 4 + r;
            int col = t * 16 + lm;
            if (row < N_NODES) Cb[(size_t)row * C_PAD + col] = f2bf(acc[t][r]);
        }
    }
}

// ---------------- agg1: quarter-sliced, 8 edges/instr, prefetched edata ----------------
// Block b: quarter q=b&3 (XCD %8 round-robin -> each XCD pair owns a 2.5MB slice),
// node i=(b>>2)*4+wave. Wave: 8 groups of 8 lanes; group g = edge k+g; lane covers
// 8 features (ushort8, 16B) -> one 128B line per edge. Reduce via shfl_xor(8,16,32).

__global__ __launch_bounds__(256) void agg1_kernel(const unsigned short* __restrict__ h1b,
                                                   const int* __restrict__ rowptr,
                                                   const int2* __restrict__ edata,
                                                   const float* __restrict__ dinv,
                                                   const float* __restrict__ b1,
                                                   unsigned short* __restrict__ hrb) {
    const int b = blockIdx.x;
    const int q = b & 3;
    const int w = threadIdx.x >> 6;
    const int lane = threadIdx.x & 63;
    const int g = lane >> 3;          // edge slot 0..7
    const int lm = lane & 7;          // feature octet
    const int i = (b >> 2) * 4 + w;   // node
    const int fbase = q * 64 + lm * 8;
    const int rb = rowptr[i], re = rowptr[i + 1];
    float acc[8] = {0.f, 0.f, 0.f, 0.f, 0.f, 0.f, 0.f, 0.f};
    int2 e = edata[rb + g];           // slack-padded, safe
#pragma unroll 2
    for (int k = rb; k < re; k += 8) {
        int2 en = edata[k + 8 + g];   // prefetch next iteration (<= E+14, in slack)
        const bool valid = (k + g) < re;
        const int s = valid ? e.x : 0;
        const float wgt = valid ? __int_as_float(e.y) : 0.f;
        ushort8_t v = *(const ushort8_t*)&h1b[((size_t)s << 8) + fbase];
#pragma unroll
        for (int j = 0; j < 8; ++j) acc[j] = fmaf(wgt, bf2f(v[j]), acc[j]);
        e = en;
    }
#pragma unroll
    for (int j = 0; j < 8; ++j) {
        acc[j] += __shfl_xor(acc[j], 8, 64);
        acc[j] += __shfl_xor(acc[j], 16, 64);
        acc[j] += __shfl_xor(acc[j], 32, 64);
    }
    if (lane < 8) {
        const float di = dinv[i];
        const float ws = di * di;
        ushort8_t sv = *(const ushort8_t*)&h1b[((size_t)i << 8) + fbase];
        float4 bb0 = *(const float4*)&b1[fbase];
        float4 bb1 = *(const float4*)&b1[fbase + 4];
        float bbv[8] = {bb0.x, bb0.y, bb0.z, bb0.w, bb1.x, bb1.y, bb1.z, bb1.w};
        ushort8_t o;
#pragma unroll
        for (int j = 0; j < 8; ++j) {
            float r = fmaf(ws, bf2f(sv[j]), acc[j]) + bbv[j];
            o[j] = f2bf(fmaxf(r, 0.f));
        }
        *(ushort8_t*)&hrb[((size_t)i << 8) + fbase] = o;
    }
}

// ---------------- agg2: wave/node, 8 edges/instr, prefetched edata ----------------

__global__ __launch_bounds__(256) void agg2_kernel(const unsigned short* __restrict__ h2b,
                                                   const int* __restrict__ rowptr,
                                                   const int2* __restrict__ edata,
                                                   const float* __restrict__ dinv,
                                                   const float* __restrict__ b2,
                                                   float* __restrict__ out) {
    const int i = (blockIdx.x * 256 + threadIdx.x) >> 6;   // node
    const int lane = threadIdx.x & 63;
    const int g = lane >> 3;          // edge slot 0..7
    const int lm = lane & 7;          // col octet
    const int c0 = lm * 8;
    const int rb = rowptr[i], re = rowptr[i + 1];
    float acc[8] = {0.f, 0.f, 0.f, 0.f, 0.f, 0.f, 0.f, 0.f};
    int2 e = edata[rb + g];
#pragma unroll 2
    for (int k = rb; k < re; k += 8) {
        int2 en = edata[k + 8 + g];
        const bool valid = (k + g) < re;
        const int s = valid ? e.x : 0;
        const float wgt = valid ? __int_as_float(e.y) : 0.f;
        ushort8_t v = *(const ushort8_t*)&h2b[((size_t)s << 6) + c0];
#pragma unroll
        for (int j = 0; j < 8; ++j) acc[j] = fmaf(wgt, bf2f(v[j]), acc[j]);
        e = en;
    }
#pragma unroll
    for (int j = 0; j < 8; ++j) {
        acc[j] += __shfl_xor(acc[j], 8, 64);
        acc[j] += __shfl_xor(acc[j], 16, 64);
        acc[j] += __shfl_xor(acc[j], 32, 64);
    }
    if (lane < 5) {                   // lanes 0..4 cover cols 0..39
        const float di = dinv[i];
        const float ws = di * di;
        ushort8_t sv = *(const ushort8_t*)&h2b[((size_t)i << 6) + c0];
        float4 bb0 = *(const float4*)&b2[c0];
        float4 bb1 = *(const float4*)&b2[c0 + 4];
        float bbv[8] = {bb0.x, bb0.y, bb0.z, bb0.w, bb1.x, bb1.y, bb1.z, bb1.w};
        float r[8];
#pragma unroll
        for (int j = 0; j < 8; ++j) r[j] = fmaf(ws, bf2f(sv[j]), acc[j]) + bbv[j];
        float* op = &out[(size_t)i * C_DIM + c0];
        *(float4*)op = make_float4(r[0], r[1], r[2], r[3]);
        *(float4*)(op + 4) = make_float4(r[4], r[5], r[6], r[7]);
    }
}

// ---------------- launch ----------------

extern "C" void kernel_launch(void* const* d_in, const int* in_sizes, int n_in,
                              void* d_out, int out_size, void* d_ws, size_t ws_size,
                              hipStream_t stream) {
    const float* x   = (const float*)d_in[0];
    const int*   ei  = (const int*)d_in[1];
    const float* W1  = (const float*)d_in[2];
    const float* b1  = (const float*)d_in[3];
    const float* W2  = (const float*)d_in[4];
    const float* b2  = (const float*)d_in[5];
    float* out = (float*)d_out;

    const int* src = ei;            // edge_index[0]
    const int* dst = ei + E_EDGES;  // edge_index[1]

    // workspace layout, 128B-aligned. Total ~28.8 MB.
    char* ws = (char*)d_ws;
    int*            cnt    = (int*)(ws + 0);            //   80000 B
    float*          dinv   = (float*)(ws + 80128);      //   80000 B
    int*            rowptr = (int*)(ws + 160128);       //   80004 B
    int*            cursor = (int*)(ws + 240256);       //   80000 B
    int*            bsum   = (int*)(ws + 320256);       //     320 B
    int2*           edata  = (int2*)(ws + 320640);      // (E+16)*8 = 5120128 B
    unsigned short* w1t    = (unsigned short*)(ws + 5440768);   //   262144 B
    unsigned short* w2t    = (unsigned short*)(ws + 5702912);   //    32768 B
    unsigned short* h1b    = (unsigned short*)(ws + 5735680);   // 10240000 B
    unsigned short* hrb    = (unsigned short*)(ws + 15975680);  // 10240000 B
    unsigned short* h2b    = (unsigned short*)(ws + 26215680);  //  2560000 B

    hipMemsetAsync(cnt, 0, N_NODES * sizeof(int), stream);

    count_kernel<<<(E_EDGES + 255) / 256, 256, 0, stream>>>(dst, cnt);
    bsum_kernel<<<NBLK, 256, 0, stream>>>(cnt, bsum);
    rowptr_kernel<<<NBLK, 256, 0, stream>>>(cnt, bsum, rowptr, cursor, dinv);
    fill_kernel<<<(E_EDGES + 16 + 255) / 256, 256, 0, stream>>>(src, dst, cursor, dinv, edata);

    wt_kernel<<<(F_IN * H_DIM + H_DIM * C_PAD) / 256, 256, 0, stream>>>(W1, W2, w1t, w2t);

    gemm1_kernel<<<(N_NODES + 63) / 64, 256, 0, stream>>>(x, w1t, h1b);

    agg1_kernel<<<N_NODES, 256, 0, stream>>>(h1b, rowptr, edata, dinv, b1, hrb);

    gemm2_kernel<<<(N_NODES + 63) / 64, 256, 0, stream>>>(hrb, w2t, h2b);

    agg2_kernel<<<N_NODES / 4, 256, 0, stream>>>(h2b, rowptr, edata, dinv, b2, out);
}